// Round 16
// baseline (206.771 us; speedup 1.0000x reference)
//
#include <hip/hip_runtime.h>
#include <hip/hip_bf16.h>
#include <math.h>

#define D_MODEL 1024
#define NH 16
#define HD 64
#define SEQ 2048
#define BATCH 2
#define NTOK (BATCH*SEQ)   // 4096

typedef short bf16x8 __attribute__((ext_vector_type(8)));
typedef short s4 __attribute__((ext_vector_type(4)));
typedef float f32x4 __attribute__((ext_vector_type(4)));
typedef unsigned short us4 __attribute__((ext_vector_type(4)));

#define MFMA(a,b,c) __builtin_amdgcn_mfma_f32_16x16x32_bf16(a,b,c,0,0,0)

union bfu { __hip_bfloat16 b; unsigned short u; };
__device__ __forceinline__ unsigned short f2b(float f){ bfu t; t.b = __float2bfloat16(f); return t.u; }
__device__ __forceinline__ float b2f(unsigned short u){ bfu t; t.u = u; return __bfloat162float(t.b); }
// fast RNE f32->bf16 bit trick (finite values only)
__device__ __forceinline__ unsigned short f2bf(float f){
    unsigned int u = __float_as_uint(f);
    u += 0x7FFFu + ((u >> 16) & 1u);
    return (unsigned short)(u >> 16);
}

// async global->LDS, 16B per lane
__device__ __forceinline__ void g2l16(const unsigned short* g, unsigned short* l){
    __builtin_amdgcn_global_load_lds(
        (const __attribute__((address_space(1))) unsigned int*)g,
        (__attribute__((address_space(3))) unsigned int*)l, 16, 0, 0);
}

// inline dtype detection (R14): sample first 256 words of x (512 exponent
// fields). f32 -> ~22% of fields have (u&0x7F80)>=0x4800 (~112 hits);
// bf16 (|x| < 2^17) -> 0 hits. Threshold 16: misclassification prob ~0.
__device__ __forceinline__ int detect_flag(const unsigned int* xraw,
                                           int tid, int* cnts){
    unsigned int v = xraw[tid & 255];
    int local = ((v & 0x7F80u) >= 0x4800u) + (((v>>16) & 0x7F80u) >= 0x4800u);
    #pragma unroll
    for (int s=1; s<64; s<<=1) local += __shfl_xor(local, s, 64);
    if ((tid & 63) == 0) cnts[tid>>6] = local;
    __syncthreads();
    return (cnts[0] + cnts[1] + cnts[2] + cnts[3]) > 16;
}

// counted-vmcnt pipeline primitives (qkv only): raw barrier = NO implicit
// vmcnt drain (unlike __syncthreads). sched_barrier(0) pins LDS ops on the
// correct side of each barrier (rule #18).
#define WAITVM(N) asm volatile("s_waitcnt vmcnt(" #N ")" ::: "memory")
#define RBAR do{ __builtin_amdgcn_s_barrier(); __builtin_amdgcn_sched_barrier(0); }while(0)

// ---- d_ws layout, in u16 units --------------------------------------------
#define OFF_X   128L
#define OFF_WQ  (OFF_X  + 4194304L)
#define OFF_BQ  (OFF_WQ + 3145728L)
#define OFF_WP  (OFF_BQ + 3072L)
#define OFF_BP  (OFF_WP + 1048576L)
#define OFF_QN  (OFF_BP + 1024L)
#define OFF_KN  (OFF_QN + 64L)
#define OFF_Q   (OFF_KN + 64L)
#define OFF_K   (OFF_Q  + 4194304L)      // swizzled K tile-chunk layout
#define OFF_V   (OFF_K  + 4194304L)      // swizzled V tile-chunk layout
#define OFF_A   (OFF_V  + 4194304L)

// Tile-chunk layouts (per bh, per 64-key tile, 4096 shorts):
//   K: element (kl, d) at short (kl*8 + ((d>>3) ^ (kl&7)))*8 + (d&7)
//   V: pi-relabeled chunk-of-4 layout. ch = kl>>2, m = kl&3:
//      element (kl, d) at short d*64 + f*4 + m,
//        f = (ch&3)*4 + (((d>>1) + (ch>>2)) & 3)
//
// GEMM LDS tiles (qkv/proj): [rows][32] shorts, 4 chunks of 8/row,
// chunk k of row r stored at slot r*4 + (k ^ ((r>>1)&3)), elem kk&7.
// Linear LDS dest + inverse-swizzled global source (rule 21). Frag read
// slot = quad ^ ((c>>1)&3): 2-way max = free (BANK_CONFLICT==0 since R3).
//
// Pipeline ledger (ALL measured on this problem):
//   R4 stage->drain->compute        qkv 61.7us
//   R6/R7 dbuf + __syncthreads      qkv 69.6/71.6 (barrier vmcnt(0) drain)
//   R8 depth-2 counted vmcnt(4)     qkv 59.4us
//   R11 depth-3 counted vmcnt(8)    qkv 57.0us   <- qkv keeps this
//   R12/R13 B-direct-from-global    NET NEGATIVE (convert permutation cost
//     either direction > qkv gain); branch closed.
//   counted-vmcnt on proj (R8) / attn (R9): REGRESSED -> both keep R7 dbuf
//     (cross-block TLP already hides their drains; m114 mechanism).
//   R14 inline detect (2 fewer dispatches): 205.1 -> 203.3 (BEST, passed).
//   R15 attn XCD-locality swizzle: TRIPWIRE FAIL (launch_once vs graph
//     divergence, accuracy OK). Mapping is provably deterministic; either
//     a latent timing race exposed by the new XCD scheduling or a flaky
//     tripwire. Unexplained divergence -> do not ship; branch closed.
//     R16 = R14 verbatim (also the control run for flake-vs-real).
//   Cross-round noise on "rest" is +-4us with identical code (R7 vs R10).
// NOTE (R3): NO min-occupancy launch_bounds on qkv (VGPR cap -> spill).

// ---------------------------------------------------------------------------
// canonicalize inputs to bf16, vectorized 4-wide (inline dtype detection).
// ---------------------------------------------------------------------------
__global__ __launch_bounds__(256) void convert_kernel(
    const void* __restrict__ x,  const void* __restrict__ wq,
    const void* __restrict__ bq, const void* __restrict__ wp,
    const void* __restrict__ bp, const void* __restrict__ qn,
    const void* __restrict__ kn, unsigned short* __restrict__ ws)
{
    __shared__ int cnts[4];
    const int flag = detect_flag((const unsigned int*)x, threadIdx.x, cnts);
    long i = (long)blockIdx.x*blockDim.x + threadIdx.x;
    const long stride = (long)gridDim.x*blockDim.x;
    const long NCH = 2098208L;
    for (; i < NCH; i += stride){
        long j = i; const void* src; long off;
        if (j < 1048576L)                  { src = x;  off = OFF_X;  }
        else if ((j -= 1048576L) < 786432L){ src = wq; off = OFF_WQ; }
        else if ((j -= 786432L)  < 768L)   { src = bq; off = OFF_BQ; }
        else if ((j -= 768L)     < 262144L){ src = wp; off = OFF_WP; }
        else if ((j -= 262144L)  < 256L)   { src = bp; off = OFF_BP; }
        else if ((j -= 256L)     < 16L)    { src = qn; off = OFF_QN; }
        else      { j -= 16L;                src = kn; off = OFF_KN; }
        us4 o;
        if (flag){
            float4 v = ((const float4*)src)[j];
            o.x = f2b(v.x); o.y = f2b(v.y); o.z = f2b(v.z); o.w = f2b(v.w);
        } else {
            o = ((const us4*)src)[j];
        }
        *(us4*)(ws + off + j*4) = o;
    }
}

// ---------------------------------------------------------------------------
// Kernel 1: qkv = x @ Wqkv^T + bqkv, fused per-head RMS norm on q,k.
// BK=32, depth-3 counted-vmcnt pipeline (R11, measured 57.0us): 6 static
// buffers (48KB LDS, 3 blocks/CU), steady-state vmcnt(8) = 2 tiles in
// flight = 2 compute phases of latency cover. Epilogue drains 8/8/8/4/0.
// K and V epilogues write the attn tile-chunk layouts. Q is pre-scaled by
// log2(e)/8 so attn softmax is a bare v_exp_f32.
// ---------------------------------------------------------------------------
__global__ __launch_bounds__(256) void qkv_kernel(
    const unsigned short* __restrict__ x,
    const unsigned short* __restrict__ Wqkv,
    const unsigned short* __restrict__ bqkv,
    const unsigned short* __restrict__ qn_w,
    const unsigned short* __restrict__ kn_w,
    unsigned short* __restrict__ qbuf,
    unsigned short* __restrict__ kbuf,
    unsigned short* __restrict__ vbuf)
{
    __shared__ __align__(16) unsigned short tA0[128*32];
    __shared__ __align__(16) unsigned short tA1[128*32];
    __shared__ __align__(16) unsigned short tA2[128*32];
    __shared__ __align__(16) unsigned short tB0[128*32];
    __shared__ __align__(16) unsigned short tB1[128*32];
    __shared__ __align__(16) unsigned short tB2[128*32];
    const int tid  = threadIdx.x;
    const int w    = tid >> 6, lane = tid & 63, quad = lane >> 4, c = lane & 15;
    const int m0 = blockIdx.y*128, n0 = blockIdx.x*128;
    const int am = (w>>1)*64, bn = (w&1)*64;
    const int kq = quad ^ ((c>>1)&3);

    f32x4 acc[4][4];
    for (int mi=0;mi<4;mi++) for (int ni=0;ni<4;ni++) acc[mi][ni] = {0.f,0.f,0.f,0.f};

    // staging: slot i covers (row r=i>>2, chunk i&3); fetch global chunk
    // (i&3)^((r>>1)&3) so the linear LDS write realizes the swizzle.
    const int i0 = tid, i1 = tid + 256;
    const int r0 = i0>>2, cc0 = (i0&3) ^ ((r0>>1)&3);
    const int r1 = i1>>2, cc1 = (i1&3) ^ ((r1>>1)&3);
    const long gaA0 = (long)(m0 + r0)*D_MODEL + cc0*8;
    const long gaA1 = (long)(m0 + r1)*D_MODEL + cc1*8;
    const long gbB0 = (long)(n0 + r0)*D_MODEL + cc0*8;
    const long gbB1 = (long)(n0 + r1)*D_MODEL + cc1*8;

#define QKV_STAGE(BUFA, BUFB, T) do{ const int kk_ = (T)*32; \
    g2l16(x    + gaA0 + kk_, BUFA + i0*8); \
    g2l16(x    + gaA1 + kk_, BUFA + i1*8); \
    g2l16(Wqkv + gbB0 + kk_, BUFB + i0*8); \
    g2l16(Wqkv + gbB1 + kk_, BUFB + i1*8); \
    __builtin_amdgcn_sched_barrier(0); }while(0)

#define QKV_COMP(BUFA, BUFB) do{ \
    bf16x8 a_[4], b_[4]; \
    _Pragma("unroll") \
    for (int mi=0;mi<4;mi++) \
        a_[mi] = *(const bf16x8*)(BUFA + ((am + mi*16 + c)*4 + kq)*8); \
    _Pragma("unroll") \
    for (int ni=0;ni<4;ni++) \
        b_[ni] = *(const bf16x8*)(BUFB + ((bn + ni*16 + c)*4 + kq)*8); \
    _Pragma("unroll") \
    for (int mi=0;mi<4;mi++) \
        _Pragma("unroll") \
        for (int ni=0;ni<4;ni++) \
            acc[mi][ni] = MFMA(a_[mi], b_[ni], acc[mi][ni]); }while(0)

    QKV_STAGE(tA0, tB0, 0);
    QKV_STAGE(tA1, tB1, 1);
    QKV_STAGE(tA2, tB2, 2);

    // tiles 0..26 in the loop; buffer = tile mod 3.
    for (int t=0; t<27; t+=3){
        WAITVM(8); RBAR;          // tile t landed (t+1,t+2 in flight)
        QKV_COMP(tA0, tB0);
        RBAR;                     // all waves done reading buf0
        QKV_STAGE(tA0, tB0, t+3);
        WAITVM(8); RBAR;          // tile t+1 landed
        QKV_COMP(tA1, tB1);
        RBAR;
        QKV_STAGE(tA1, tB1, t+4);
        WAITVM(8); RBAR;          // tile t+2 landed
        QKV_COMP(tA2, tB2);
        RBAR;
        QKV_STAGE(tA2, tB2, t+5);
    }
    // epilogue: tiles 27(b0) 28(b1) 29(b2) staged; stage 30(b0) 31(b1).
    WAITVM(8); RBAR;              // tile 27 landed
    QKV_COMP(tA0, tB0);
    RBAR;
    QKV_STAGE(tA0, tB0, 30);
    WAITVM(8); RBAR;              // tile 28 landed
    QKV_COMP(tA1, tB1);
    RBAR;
    QKV_STAGE(tA1, tB1, 31);
    WAITVM(8); RBAR;              // tile 29 landed (30,31 in flight)
    QKV_COMP(tA2, tB2);
    WAITVM(4); RBAR;              // tile 30 landed
    QKV_COMP(tA0, tB0);
    WAITVM(0); RBAR;              // tile 31 landed
    QKV_COMP(tA1, tB1);
#undef QKV_STAGE
#undef QKV_COMP

    const int nw = n0 + bn, mw = m0 + am;
    const int region = nw >> 10;          // 0=q, 1=k, 2=v
    const int h      = (nw & 1023) >> 6;
    float bias[4], wn[4];
    for (int ni=0;ni<4;ni++){
        bias[ni] = b2f(bqkv[nw + ni*16 + c]);
        wn[ni]   = 1.0f;
    }
    // fold softmax scale*log2(e) = (1/8)*1.4426950 into the stored Q so the
    // attention kernel's softmax is a single v_exp_f32 per score.
    if (region==0) for (int ni=0;ni<4;ni++) wn[ni] = b2f(qn_w[ni*16+c]) * 0.18033688f;
    if (region==1) for (int ni=0;ni<4;ni++) wn[ni] = b2f(kn_w[ni*16+c]);

    for (int mi=0;mi<4;mi++){
        for (int ni=0;ni<4;ni++)
            for (int r=0;r<4;r++) acc[mi][ni][r] += bias[ni];

        float scale_r[4];
        if (region < 2){
            for (int r=0;r<4;r++){
                float ss = 0.f;
                for (int ni=0;ni<4;ni++){ float v2 = acc[mi][ni][r]; ss += v2*v2; }
                ss += __shfl_xor(ss, 1, 64);
                ss += __shfl_xor(ss, 2, 64);
                ss += __shfl_xor(ss, 4, 64);
                ss += __shfl_xor(ss, 8, 64);
                scale_r[r] = rsqrtf(ss*(1.0f/64.0f) + 1e-6f);
            }
        } else {
            for (int r=0;r<4;r++) scale_r[r] = 1.0f;
        }

        for (int r=0;r<4;r++){
            int m = mw + mi*16 + quad*4 + r;
            int bidx = m >> 11, s = m & 2047;
            long bb = (long)(bidx*NH + h)*SEQ*HD;
            if (region == 0){
                long base = bb + (long)s*HD;
                for (int ni=0;ni<4;ni++)
                    qbuf[base + ni*16 + c] = f2bf(acc[mi][ni][r] * scale_r[r] * wn[ni]);
            } else if (region == 1){
                long tb = bb + (long)(s>>6)*4096;
                for (int ni=0;ni<4;ni++){
                    int d = ni*16 + c;
                    long idx = tb + (long)((s&63)*8 + ((d>>3) ^ (s&7)))*8 + (d&7);
                    kbuf[idx] = f2bf(acc[mi][ni][r] * scale_r[r] * wn[ni]);
                }
            } else {
                // V pi-relabeled chunk layout: kl = s&63, ch = kl>>2, m = kl&3
                long tb = bb + (long)(s>>6)*4096;
                int ch2  = (s>>4)&3;          // ch>>2
                int fb   = ((s>>2)&3)*4;      // (ch&3)*4
                int mloc = s&3;
                for (int ni=0;ni<4;ni++){
                    int d = ni*16 + c;
                    int f = fb + (((d>>1) + ch2)&3);
                    long idx = tb + (long)d*64 + f*4 + mloc;
                    vbuf[idx] = f2bf(acc[mi][ni][r]);
                }
            }
        }
    }
}

// ---------------------------------------------------------------------------
// Kernel 2: attention. 64 qrows/block, 4 waves x 16 qrows, grid (32,32) =
// 1024 blocks -> 4 blocks/CU (LDS 32 KiB), 4 waves/SIMD.
//
// S^T = K*Q^T: C-frag holds key = mt*16+quad*4+r (row), qrow = c (col).
// p = v_exp_f32(z) raw (scale folded into Q at qkv; constant offset cancels
// in O/l). P pairs truncate-packed with v_perm -> pk[mt][w2].
//
// PV with NO relayout: the C-frag -> operand-frag transpose is a uniform
// bit-permutation pi of the 32-wide contraction index k; MFMA contraction is
// invariant under relabeling k on BOTH operands, so pk words feed DIRECTLY
// as the B-operand (O^T = V^T P^T) and V is stored pre-permuted by pi in LDS
// (chunk-of-4 f-swizzle above). Output C-frag: O[qrow=c][d=nt*16+quad*4+r];
// denominator lane-local, stores packed 8B.
// R7 form (measured best): static dbuf names + __syncthreads. The R9
// counted-vmcnt port REGRESSED (76.5us): 4 independent blocks/CU already
// hide the barrier drain via TLP; rigid fences only subtract.
// ---------------------------------------------------------------------------
__global__ __launch_bounds__(256, 4) void attn_kernel(
    const unsigned short* __restrict__ qbuf,
    const unsigned short* __restrict__ kts,
    const unsigned short* __restrict__ vts,
    unsigned short* __restrict__ abuf)
{
    const int tid = threadIdx.x, w = tid>>6, lane = tid&63, quad = lane>>4, c = lane&15;
    const int bh = blockIdx.y, qt = blockIdx.x;
    const unsigned short* qb = qbuf + (long)bh*SEQ*HD;
    const unsigned short* kb = kts + (long)bh*SEQ*HD;   // tile-chunk layout
    const unsigned short* vb = vts + (long)bh*SEQ*HD;
    const int qbase = qt*64 + w*16;
    const int cq = c & 7;

    __shared__ __align__(16) unsigned short KT0[4096];
    __shared__ __align__(16) unsigned short KT1[4096];
    __shared__ __align__(16) unsigned short VT0[4096];
    __shared__ __align__(16) unsigned short VT1[4096];

    // Q frags (B-operand of S^T): lane holds Q[qbase+c][ks*32+quad*8+j]
    bf16x8 aq[2];
    #pragma unroll
    for (int ks=0;ks<2;ks++)
        aq[ks] = *(const bf16x8*)(qb + (long)(qbase + c)*HD + ks*32 + quad*8);

    f32x4 o[4];
    #pragma unroll
    for (int nt=0;nt<4;nt++) o[nt] = {0.f,0.f,0.f,0.f};
    f32x4 l4 = {0.f,0.f,0.f,0.f};

#define STAGE2(SRC, DST) do{ \
    g2l16((SRC) + tid*8,        DST + tid*8); \
    g2l16((SRC) + 2048 + tid*8, DST + 2048 + tid*8); }while(0)

#define ATTN_TILE(KTB, VTB) do{ \
    bf16x8 kf_[4][2]; \
    _Pragma("unroll") \
    for (int mt=0;mt<4;mt++) \
        _Pragma("unroll") \
        for (int ks=0;ks<2;ks++) \
            kf_[mt][ks] = *(const bf16x8*)(KTB + ((mt*16+c)*8 + ((ks*4+quad)^cq))*8); \
    f32x4 z4_[4]; \
    _Pragma("unroll") \
    for (int mt=0;mt<4;mt++){ \
        f32x4 t_ = {0.f,0.f,0.f,0.f}; \
        t_ = MFMA(kf_[mt][0], aq[0], t_); \
        t_ = MFMA(kf_[mt][1], aq[1], t_); \
        z4_[mt] = t_; \
    } \
    unsigned int pk_[4][2]; \
    _Pragma("unroll") \
    for (int mt=0;mt<4;mt++){ \
        float p0 = __builtin_amdgcn_exp2f(z4_[mt][0]); \
        float p1 = __builtin_amdgcn_exp2f(z4_[mt][1]); \
        float p2 = __builtin_amdgcn_exp2f(z4_[mt][2]); \
        float p3 = __builtin_amdgcn_exp2f(z4_[mt][3]); \
        l4[0] += p0; l4[1] += p1; l4[2] += p2; l4[3] += p3; \
        pk_[mt][0] = __builtin_amdgcn_perm(__float_as_uint(p1), __float_as_uint(p0), 0x07060302u); \
        pk_[mt][1] = __builtin_amdgcn_perm(__float_as_uint(p3), __float_as_uint(p2), 0x07060302u); \
    } \
    _Pragma("unroll") \
    for (int ks=0;ks<2;ks++){ \
        union { unsigned int u[4]; bf16x8 v; } pB_; \
        pB_.u[0] = pk_[2*ks][0];   pB_.u[1] = pk_[2*ks][1]; \
        pB_.u[2] = pk_[2*ks+1][0]; pB_.u[3] = pk_[2*ks+1][1]; \
        _Pragma("unroll") \
        for (int nt=0;nt<4;nt++){ \
            const int dv_ = nt*16 + c; \
            const unsigned short* vbase_ = VTB + dv_*64; \
            int flo_ = quad*4 + (((dv_>>1) + ks*2    )&3); \
            int fhi_ = quad*4 + (((dv_>>1) + ks*2 + 1)&3); \
            uint2 lo_ = *(const uint2*)(vbase_ + flo_*4); \
            uint2 hi_ = *(const uint2*)(vbase_ + fhi_*4); \
            union { unsigned int u[4]; bf16x8 v; } vv_; \
            vv_.u[0]=lo_.x; vv_.u[1]=lo_.y; vv_.u[2]=hi_.x; vv_.u[3]=hi_.y; \
            o[nt] = MFMA(vv_.v, pB_.v, o[nt]); \
        } \
    } }while(0)

    STAGE2(kb, KT0); STAGE2(vb, VT0);
    __syncthreads();

    for (int kt2=0; kt2<SEQ/64; kt2+=2){
        STAGE2(kb + (kt2+1)*4096, KT1);   // kt2+1 <= 31 always
        STAGE2(vb + (kt2+1)*4096, VT1);
        ATTN_TILE(KT0, VT0);
        __syncthreads();
        if (kt2+2 < SEQ/64){
            STAGE2(kb + (kt2+2)*4096, KT0);
            STAGE2(vb + (kt2+2)*4096, VT0);
        }
        ATTN_TILE(KT1, VT1);
        __syncthreads();
    }
#undef STAGE2
#undef ATTN_TILE

    // denominator: lane-local partial for qrow c; reduce across quads.
    float l_loc = (l4[0]+l4[1]) + (l4[2]+l4[3]);
    l_loc += __shfl_xor(l_loc, 16, 64);
    l_loc += __shfl_xor(l_loc, 32, 64);
    float inv = 1.0f / l_loc;

    const int b = bh >> 4, h = bh & 15;
    long base = ((long)(b*SEQ + qbase + c)*NH + h)*HD;
    #pragma unroll
    for (int nt=0;nt<4;nt++){
        us4 pkd;
        #pragma unroll
        for (int r=0;r<4;r++) pkd[r] = f2bf(o[nt][r]*inv);
        *(us4*)(abuf + base + nt*16 + quad*4) = pkd;
    }
}

// ---------------------------------------------------------------------------
// Kernel 3: out = attn @ Wproj^T + bproj. 128x64 tile, BK=32, static-name
// double-buffered prefetch + __syncthreads (R7 form — counted-vmcnt
// REGRESSED proj ~14us in R8). 512 blocks = 2/CU. Inline dtype detection
// for the output-format flag.
// ---------------------------------------------------------------------------
__global__ __launch_bounds__(256) void proj_kernel(
    const unsigned short* __restrict__ abuf,
    const unsigned short* __restrict__ Wp,
    const unsigned short* __restrict__ bp,
    void* __restrict__ outv,
    const unsigned int* __restrict__ xraw)
{
    __shared__ __align__(16) unsigned short tA0[128*32];
    __shared__ __align__(16) unsigned short tA1[128*32];
    __shared__ __align__(16) unsigned short tB0[64*32];
    __shared__ __align__(16) unsigned short tB1[64*32];
    __shared__ int cnts[4];
    const int tid  = threadIdx.x;
    const int flag = detect_flag(xraw, tid, cnts);
    const int w    = tid >> 6, lane = tid & 63, quad = lane >> 4, c = lane & 15;
    const int m0 = blockIdx.y*128, n0 = blockIdx.x*64;
    const int am = (w>>1)*64, bn = (w&1)*32;
    const int kq = quad ^ ((c>>1)&3);

    f32x4 acc[4][2];
    for (int mi=0;mi<4;mi++) for (int ni=0;ni<2;ni++) acc[mi][ni] = {0.f,0.f,0.f,0.f};

    const int i0 = tid, i1 = tid + 256;
    const int r0 = i0>>2, cc0 = (i0&3) ^ ((r0>>1)&3);
    const int r1 = i1>>2, cc1 = (i1&3) ^ ((r1>>1)&3);
    const long gaA0 = (long)(m0 + r0)*D_MODEL + cc0*8;
    const long gaA1 = (long)(m0 + r1)*D_MODEL + cc1*8;
    const long gbB0 = (long)(n0 + r0)*D_MODEL + cc0*8;   // r0 < 64 for B

#define PROJ_STAGE(BUFA, BUFB, T) do{ const int kk_ = (T)*32; \
    g2l16(abuf + gaA0 + kk_, BUFA + i0*8); \
    g2l16(abuf + gaA1 + kk_, BUFA + i1*8); \
    g2l16(Wp   + gbB0 + kk_, BUFB + i0*8); }while(0)

#define PROJ_COMP(BUFA, BUFB) do{ \
    bf16x8 a_[4], b_[2]; \
    _Pragma("unroll") \
    for (int mi=0;mi<4;mi++) \
        a_[mi] = *(const bf16x8*)(BUFA + ((am + mi*16 + c)*4 + kq)*8); \
    _Pragma("unroll") \
    for (int ni=0;ni<2;ni++) \
        b_[ni] = *(const bf16x8*)(BUFB + ((bn + ni*16 + c)*4 + kq)*8); \
    _Pragma("unroll") \
    for (int mi=0;mi<4;mi++) \
        _Pragma("unroll") \
        for (int ni=0;ni<2;ni++) \
            acc[mi][ni] = MFMA(a_[mi], b_[ni], acc[mi][ni]); }while(0)

    PROJ_STAGE(tA0, tB0, 0);
    __syncthreads();

    for (int t=0; t<32; t+=2){
        PROJ_STAGE(tA1, tB1, t+1);       // t+1 <= 31 always
        PROJ_COMP(tA0, tB0);
        __syncthreads();
        if (t+2 < 32) PROJ_STAGE(tA0, tB0, t+2);
        PROJ_COMP(tA1, tB1);
        __syncthreads();
    }
#undef PROJ_STAGE
#undef PROJ_COMP

    float bias[2];
    for (int ni=0;ni<2;ni++) bias[ni] = b2f(bp[n0 + bn + ni*16 + c]);

    for (int mi=0;mi<4;mi++)
        for (int r=0;r<4;r++){
            long m = m0 + am + mi*16 + quad*4 + r;
            for (int ni=0;ni<2;ni++){
                float val = acc[mi][ni][r] + bias[ni];
                long idx = m*D_MODEL + n0 + bn + ni*16 + c;
                if (flag) ((float*)outv)[idx] = val;
                else      ((unsigned short*)outv)[idx] = f2bf(val);
            }
        }
}

extern "C" void kernel_launch(void* const* d_in, const int* in_sizes, int n_in,
                              void* d_out, int out_size, void* d_ws, size_t ws_size,
                              hipStream_t stream)
{
    unsigned short* ws = (unsigned short*)d_ws;

    hipLaunchKernelGGL(convert_kernel, dim3(2048), dim3(256), 0, stream,
                       d_in[0], d_in[1], d_in[2], d_in[3], d_in[4], d_in[5], d_in[6],
                       ws);
    hipLaunchKernelGGL(qkv_kernel,  dim3(24,32), dim3(256), 0, stream,
                       ws+OFF_X, ws+OFF_WQ, ws+OFF_BQ, ws+OFF_QN, ws+OFF_KN,
                       ws+OFF_Q, ws+OFF_K, ws+OFF_V);
    hipLaunchKernelGGL(attn_kernel, dim3(32,32), dim3(256), 0, stream,
                       ws+OFF_Q, ws+OFF_K, ws+OFF_V, ws+OFF_A);
    hipLaunchKernelGGL(proj_kernel, dim3(16,32), dim3(256), 0, stream,
                       ws+OFF_A, ws+OFF_WP, ws+OFF_BP, d_out,
                       (const unsigned int*)d_in[0]);
}

// Round 18
// 200.960 us; speedup vs baseline: 1.0289x; 1.0289x over previous
//
#include <hip/hip_runtime.h>
#include <hip/hip_bf16.h>
#include <math.h>

#define D_MODEL 1024
#define NH 16
#define HD 64
#define SEQ 2048
#define BATCH 2
#define NTOK (BATCH*SEQ)   // 4096

typedef short bf16x8 __attribute__((ext_vector_type(8)));
typedef short s4 __attribute__((ext_vector_type(4)));
typedef float f32x4 __attribute__((ext_vector_type(4)));
typedef unsigned short us4 __attribute__((ext_vector_type(4)));

#define MFMA(a,b,c) __builtin_amdgcn_mfma_f32_16x16x32_bf16(a,b,c,0,0,0)

union bfu { __hip_bfloat16 b; unsigned short u; };
__device__ __forceinline__ unsigned short f2b(float f){ bfu t; t.b = __float2bfloat16(f); return t.u; }
__device__ __forceinline__ float b2f(unsigned short u){ bfu t; t.u = u; return __bfloat162float(t.b); }
// fast RNE f32->bf16 bit trick (finite values only)
__device__ __forceinline__ unsigned short f2bf(float f){
    unsigned int u = __float_as_uint(f);
    u += 0x7FFFu + ((u >> 16) & 1u);
    return (unsigned short)(u >> 16);
}

// async global->LDS, 16B per lane
__device__ __forceinline__ void g2l16(const unsigned short* g, unsigned short* l){
    __builtin_amdgcn_global_load_lds(
        (const __attribute__((address_space(1))) unsigned int*)g,
        (__attribute__((address_space(3))) unsigned int*)l, 16, 0, 0);
}

// inline dtype detection (R14): sample first 256 words of x (512 exponent
// fields). f32 -> ~22% of fields have (u&0x7F80)>=0x4800 (~112 hits);
// bf16 (|x| < 2^17) -> 0 hits. Threshold 16: misclassification prob ~0.
__device__ __forceinline__ int detect_flag(const unsigned int* xraw,
                                           int tid, int* cnts){
    unsigned int v = xraw[tid & 255];
    int local = ((v & 0x7F80u) >= 0x4800u) + (((v>>16) & 0x7F80u) >= 0x4800u);
    #pragma unroll
    for (int s=1; s<64; s<<=1) local += __shfl_xor(local, s, 64);
    if ((tid & 63) == 0) cnts[tid>>6] = local;
    __syncthreads();
    return (cnts[0] + cnts[1] + cnts[2] + cnts[3]) > 16;
}

// counted-vmcnt pipeline primitives (qkv only): raw barrier = NO implicit
// vmcnt drain (unlike __syncthreads). sched_barrier(0) pins LDS ops on the
// correct side of each barrier (rule #18).
#define WAITVM(N) asm volatile("s_waitcnt vmcnt(" #N ")" ::: "memory")
#define RBAR do{ __builtin_amdgcn_s_barrier(); __builtin_amdgcn_sched_barrier(0); }while(0)

// ---- d_ws layout, in u16 units --------------------------------------------
#define OFF_X   128L
#define OFF_WQ  (OFF_X  + 4194304L)
#define OFF_BQ  (OFF_WQ + 3145728L)
#define OFF_WP  (OFF_BQ + 3072L)
#define OFF_BP  (OFF_WP + 1048576L)
#define OFF_QN  (OFF_BP + 1024L)
#define OFF_KN  (OFF_QN + 64L)
#define OFF_Q   (OFF_KN + 64L)
#define OFF_K   (OFF_Q  + 4194304L)      // swizzled K tile-chunk layout
#define OFF_V   (OFF_K  + 4194304L)      // swizzled V tile-chunk layout
#define OFF_A   (OFF_V  + 4194304L)

// Tile-chunk layouts (per bh, per 64-key tile, 4096 shorts):
//   K: element (kl, d) at short (kl*8 + ((d>>3) ^ (kl&7)))*8 + (d&7)
//   V: pi-relabeled chunk-of-4 layout. ch = kl>>2, m = kl&3:
//      element (kl, d) at short d*64 + f*4 + m,
//        f = (ch&3)*4 + (((d>>1) + (ch>>2)) & 3)
//
// GEMM LDS tiles (qkv/proj): [rows][32] shorts, 4 chunks of 8/row,
// chunk k of row r stored at slot r*4 + (k ^ ((r>>1)&3)), elem kk&7.
// Linear LDS dest + inverse-swizzled global source (rule 21). Frag read
// slot = quad ^ ((c>>1)&3): 2-way max = free (BANK_CONFLICT==0 since R3).
//
// Pipeline ledger (ALL measured on this problem):
//   R4 stage->drain->compute        qkv 61.7us
//   R6/R7 dbuf + __syncthreads      qkv 69.6/71.6 (barrier vmcnt(0) drain)
//   R8 depth-2 counted vmcnt(4)     qkv 59.4us
//   R11 depth-3 counted vmcnt(8)    qkv 57.0us
//   R12/R13 B-direct-from-global    NET NEGATIVE; branch closed.
//   counted-vmcnt on proj (R8) / attn (R9): REGRESSED -> both keep R7 dbuf.
//   R14 inline detect: 203.3us BEST (R16 control re-pass: 206.8).
//   R15 attn XCD swizzle + R17 attn 128-row tiles: BOTH tripwire-failed
//     (launch_once vs graph divergence). Common factor: attn GRID change.
//     No race found on audit; attn launch geometry is FROZEN at (32,32).
//   R18: qkv single-barrier-per-phase. The post-compute barrier (buffer
//     protection) is redundant: at phase p's barrier every wave has
//     finished COMP(p-1), so buf((p-1)%3) is free — stage tile p+2 into
//     it AFTER the barrier. Phase = WAITVM(4); RBAR; STAGE(freed, p+2);
//     COMP(p%3). Steady outstanding = 8 loads (tiles p, p+1) -> vmcnt(4)
//     = tile p landed. Barriers halve (64 -> 34).
//   Cross-round noise on "rest" is +-4us with identical code (R7 vs R10).
// NOTE (R3): NO min-occupancy launch_bounds on qkv (VGPR cap -> spill).

// ---------------------------------------------------------------------------
// canonicalize inputs to bf16, vectorized 4-wide (inline dtype detection).
// ---------------------------------------------------------------------------
__global__ __launch_bounds__(256) void convert_kernel(
    const void* __restrict__ x,  const void* __restrict__ wq,
    const void* __restrict__ bq, const void* __restrict__ wp,
    const void* __restrict__ bp, const void* __restrict__ qn,
    const void* __restrict__ kn, unsigned short* __restrict__ ws)
{
    __shared__ int cnts[4];
    const int flag = detect_flag((const unsigned int*)x, threadIdx.x, cnts);
    long i = (long)blockIdx.x*blockDim.x + threadIdx.x;
    const long stride = (long)gridDim.x*blockDim.x;
    const long NCH = 2098208L;
    for (; i < NCH; i += stride){
        long j = i; const void* src; long off;
        if (j < 1048576L)                  { src = x;  off = OFF_X;  }
        else if ((j -= 1048576L) < 786432L){ src = wq; off = OFF_WQ; }
        else if ((j -= 786432L)  < 768L)   { src = bq; off = OFF_BQ; }
        else if ((j -= 768L)     < 262144L){ src = wp; off = OFF_WP; }
        else if ((j -= 262144L)  < 256L)   { src = bp; off = OFF_BP; }
        else if ((j -= 256L)     < 16L)    { src = qn; off = OFF_QN; }
        else      { j -= 16L;                src = kn; off = OFF_KN; }
        us4 o;
        if (flag){
            float4 v = ((const float4*)src)[j];
            o.x = f2b(v.x); o.y = f2b(v.y); o.z = f2b(v.z); o.w = f2b(v.w);
        } else {
            o = ((const us4*)src)[j];
        }
        *(us4*)(ws + off + j*4) = o;
    }
}

// ---------------------------------------------------------------------------
// Kernel 1: qkv = x @ Wqkv^T + bqkv, fused per-head RMS norm on q,k.
// BK=32, depth-3 buffers, SINGLE-barrier-per-phase counted-vmcnt pipeline
// (R18; see ledger note). K and V epilogues write the attn tile-chunk
// layouts. Q pre-scaled by log2(e)/8 so attn softmax is a bare v_exp_f32.
// ---------------------------------------------------------------------------
__global__ __launch_bounds__(256) void qkv_kernel(
    const unsigned short* __restrict__ x,
    const unsigned short* __restrict__ Wqkv,
    const unsigned short* __restrict__ bqkv,
    const unsigned short* __restrict__ qn_w,
    const unsigned short* __restrict__ kn_w,
    unsigned short* __restrict__ qbuf,
    unsigned short* __restrict__ kbuf,
    unsigned short* __restrict__ vbuf)
{
    __shared__ __align__(16) unsigned short tA0[128*32];
    __shared__ __align__(16) unsigned short tA1[128*32];
    __shared__ __align__(16) unsigned short tA2[128*32];
    __shared__ __align__(16) unsigned short tB0[128*32];
    __shared__ __align__(16) unsigned short tB1[128*32];
    __shared__ __align__(16) unsigned short tB2[128*32];
    const int tid  = threadIdx.x;
    const int w    = tid >> 6, lane = tid & 63, quad = lane >> 4, c = lane & 15;
    const int m0 = blockIdx.y*128, n0 = blockIdx.x*128;
    const int am = (w>>1)*64, bn = (w&1)*64;
    const int kq = quad ^ ((c>>1)&3);

    f32x4 acc[4][4];
    for (int mi=0;mi<4;mi++) for (int ni=0;ni<4;ni++) acc[mi][ni] = {0.f,0.f,0.f,0.f};

    // staging: slot i covers (row r=i>>2, chunk i&3); fetch global chunk
    // (i&3)^((r>>1)&3) so the linear LDS write realizes the swizzle.
    const int i0 = tid, i1 = tid + 256;
    const int r0 = i0>>2, cc0 = (i0&3) ^ ((r0>>1)&3);
    const int r1 = i1>>2, cc1 = (i1&3) ^ ((r1>>1)&3);
    const long gaA0 = (long)(m0 + r0)*D_MODEL + cc0*8;
    const long gaA1 = (long)(m0 + r1)*D_MODEL + cc1*8;
    const long gbB0 = (long)(n0 + r0)*D_MODEL + cc0*8;
    const long gbB1 = (long)(n0 + r1)*D_MODEL + cc1*8;

#define QKV_STAGE(BUFA, BUFB, T) do{ const int kk_ = (T)*32; \
    g2l16(x    + gaA0 + kk_, BUFA + i0*8); \
    g2l16(x    + gaA1 + kk_, BUFA + i1*8); \
    g2l16(Wqkv + gbB0 + kk_, BUFB + i0*8); \
    g2l16(Wqkv + gbB1 + kk_, BUFB + i1*8); \
    __builtin_amdgcn_sched_barrier(0); }while(0)

#define QKV_COMP(BUFA, BUFB) do{ \
    bf16x8 a_[4], b_[4]; \
    _Pragma("unroll") \
    for (int mi=0;mi<4;mi++) \
        a_[mi] = *(const bf16x8*)(BUFA + ((am + mi*16 + c)*4 + kq)*8); \
    _Pragma("unroll") \
    for (int ni=0;ni<4;ni++) \
        b_[ni] = *(const bf16x8*)(BUFB + ((bn + ni*16 + c)*4 + kq)*8); \
    _Pragma("unroll") \
    for (int mi=0;mi<4;mi++) \
        _Pragma("unroll") \
        for (int ni=0;ni<4;ni++) \
            acc[mi][ni] = MFMA(a_[mi], b_[ni], acc[mi][ni]); }while(0)

    QKV_STAGE(tA0, tB0, 0);
    QKV_STAGE(tA1, tB1, 1);

    // Phase p: WAITVM(4) (tile p landed; p+1 in flight) -> barrier (also
    // proves all waves finished COMP(p-1), freeing buf((p-1)%3)) ->
    // STAGE(freed buf, tile p+2) -> COMP(buf p%3). One barrier per phase.
    for (int t=0; t<30; t+=3){
        WAITVM(4); RBAR;              // tile t landed
        QKV_STAGE(tA2, tB2, t+2);     // buf2 freed by COMP(t-1) (or fresh)
        QKV_COMP(tA0, tB0);
        WAITVM(4); RBAR;              // tile t+1 landed
        QKV_STAGE(tA0, tB0, t+3);
        QKV_COMP(tA1, tB1);
        WAITVM(4); RBAR;              // tile t+2 landed
        QKV_STAGE(tA1, tB1, t+4);
        QKV_COMP(tA2, tB2);
    }
    // loop covered phases 0..29, staged tiles 2..31. Epilogue: 30, 31.
    WAITVM(4); RBAR;                  // tile 30 landed (31 in flight)
    QKV_COMP(tA0, tB0);               // 30 % 3 == 0
    WAITVM(0); RBAR;                  // tile 31 landed
    QKV_COMP(tA1, tB1);               // 31 % 3 == 1
#undef QKV_STAGE
#undef QKV_COMP

    const int nw = n0 + bn, mw = m0 + am;
    const int region = nw >> 10;          // 0=q, 1=k, 2=v
    const int h      = (nw & 1023) >> 6;
    float bias[4], wn[4];
    for (int ni=0;ni<4;ni++){
        bias[ni] = b2f(bqkv[nw + ni*16 + c]);
        wn[ni]   = 1.0f;
    }
    // fold softmax scale*log2(e) = (1/8)*1.4426950 into the stored Q so the
    // attention kernel's softmax is a single v_exp_f32 per score.
    if (region==0) for (int ni=0;ni<4;ni++) wn[ni] = b2f(qn_w[ni*16+c]) * 0.18033688f;
    if (region==1) for (int ni=0;ni<4;ni++) wn[ni] = b2f(kn_w[ni*16+c]);

    for (int mi=0;mi<4;mi++){
        for (int ni=0;ni<4;ni++)
            for (int r=0;r<4;r++) acc[mi][ni][r] += bias[ni];

        float scale_r[4];
        if (region < 2){
            for (int r=0;r<4;r++){
                float ss = 0.f;
                for (int ni=0;ni<4;ni++){ float v2 = acc[mi][ni][r]; ss += v2*v2; }
                ss += __shfl_xor(ss, 1, 64);
                ss += __shfl_xor(ss, 2, 64);
                ss += __shfl_xor(ss, 4, 64);
                ss += __shfl_xor(ss, 8, 64);
                scale_r[r] = rsqrtf(ss*(1.0f/64.0f) + 1e-6f);
            }
        } else {
            for (int r=0;r<4;r++) scale_r[r] = 1.0f;
        }

        for (int r=0;r<4;r++){
            int m = mw + mi*16 + quad*4 + r;
            int bidx = m >> 11, s = m & 2047;
            long bb = (long)(bidx*NH + h)*SEQ*HD;
            if (region == 0){
                long base = bb + (long)s*HD;
                for (int ni=0;ni<4;ni++)
                    qbuf[base + ni*16 + c] = f2bf(acc[mi][ni][r] * scale_r[r] * wn[ni]);
            } else if (region == 1){
                long tb = bb + (long)(s>>6)*4096;
                for (int ni=0;ni<4;ni++){
                    int d = ni*16 + c;
                    long idx = tb + (long)((s&63)*8 + ((d>>3) ^ (s&7)))*8 + (d&7);
                    kbuf[idx] = f2bf(acc[mi][ni][r] * scale_r[r] * wn[ni]);
                }
            } else {
                // V pi-relabeled chunk layout: kl = s&63, ch = kl>>2, m = kl&3
                long tb = bb + (long)(s>>6)*4096;
                int ch2  = (s>>4)&3;          // ch>>2
                int fb   = ((s>>2)&3)*4;      // (ch&3)*4
                int mloc = s&3;
                for (int ni=0;ni<4;ni++){
                    int d = ni*16 + c;
                    int f = fb + (((d>>1) + ch2)&3);
                    long idx = tb + (long)d*64 + f*4 + mloc;
                    vbuf[idx] = f2bf(acc[mi][ni][r]);
                }
            }
        }
    }
}

// ---------------------------------------------------------------------------
// Kernel 2: attention. 64 qrows/block, 4 waves x 16 qrows, grid (32,32) =
// 1024 blocks -> 4 blocks/CU (LDS 32 KiB), 4 waves/SIMD. GRID FROZEN
// (R15/R17 grid changes both tripwire-failed).
//
// S^T = K*Q^T: C-frag holds key = mt*16+quad*4+r (row), qrow = c (col).
// p = v_exp_f32(z) raw (scale folded into Q at qkv; constant offset cancels
// in O/l). P pairs truncate-packed with v_perm -> pk[mt][w2].
//
// PV with NO relayout: the C-frag -> operand-frag transpose is a uniform
// bit-permutation pi of the 32-wide contraction index k; MFMA contraction is
// invariant under relabeling k on BOTH operands, so pk words feed DIRECTLY
// as the B-operand (O^T = V^T P^T) and V is stored pre-permuted by pi in LDS
// (chunk-of-4 f-swizzle above). Output C-frag: O[qrow=c][d=nt*16+quad*4+r];
// denominator lane-local, stores packed 8B. R7 measured-best form.
// ---------------------------------------------------------------------------
__global__ __launch_bounds__(256, 4) void attn_kernel(
    const unsigned short* __restrict__ qbuf,
    const unsigned short* __restrict__ kts,
    const unsigned short* __restrict__ vts,
    unsigned short* __restrict__ abuf)
{
    const int tid = threadIdx.x, w = tid>>6, lane = tid&63, quad = lane>>4, c = lane&15;
    const int bh = blockIdx.y, qt = blockIdx.x;
    const unsigned short* qb = qbuf + (long)bh*SEQ*HD;
    const unsigned short* kb = kts + (long)bh*SEQ*HD;   // tile-chunk layout
    const unsigned short* vb = vts + (long)bh*SEQ*HD;
    const int qbase = qt*64 + w*16;
    const int cq = c & 7;

    __shared__ __align__(16) unsigned short KT0[4096];
    __shared__ __align__(16) unsigned short KT1[4096];
    __shared__ __align__(16) unsigned short VT0[4096];
    __shared__ __align__(16) unsigned short VT1[4096];

    // Q frags (B-operand of S^T): lane holds Q[qbase+c][ks*32+quad*8+j]
    bf16x8 aq[2];
    #pragma unroll
    for (int ks=0;ks<2;ks++)
        aq[ks] = *(const bf16x8*)(qb + (long)(qbase + c)*HD + ks*32 + quad*8);

    f32x4 o[4];
    #pragma unroll
    for (int nt=0;nt<4;nt++) o[nt] = {0.f,0.f,0.f,0.f};
    f32x4 l4 = {0.f,0.f,0.f,0.f};

#define STAGE2(SRC, DST) do{ \
    g2l16((SRC) + tid*8,        DST + tid*8); \
    g2l16((SRC) + 2048 + tid*8, DST + 2048 + tid*8); }while(0)

#define ATTN_TILE(KTB, VTB) do{ \
    bf16x8 kf_[4][2]; \
    _Pragma("unroll") \
    for (int mt=0;mt<4;mt++) \
        _Pragma("unroll") \
        for (int ks=0;ks<2;ks++) \
            kf_[mt][ks] = *(const bf16x8*)(KTB + ((mt*16+c)*8 + ((ks*4+quad)^cq))*8); \
    f32x4 z4_[4]; \
    _Pragma("unroll") \
    for (int mt=0;mt<4;mt++){ \
        f32x4 t_ = {0.f,0.f,0.f,0.f}; \
        t_ = MFMA(kf_[mt][0], aq[0], t_); \
        t_ = MFMA(kf_[mt][1], aq[1], t_); \
        z4_[mt] = t_; \
    } \
    unsigned int pk_[4][2]; \
    _Pragma("unroll") \
    for (int mt=0;mt<4;mt++){ \
        float p0 = __builtin_amdgcn_exp2f(z4_[mt][0]); \
        float p1 = __builtin_amdgcn_exp2f(z4_[mt][1]); \
        float p2 = __builtin_amdgcn_exp2f(z4_[mt][2]); \
        float p3 = __builtin_amdgcn_exp2f(z4_[mt][3]); \
        l4[0] += p0; l4[1] += p1; l4[2] += p2; l4[3] += p3; \
        pk_[mt][0] = __builtin_amdgcn_perm(__float_as_uint(p1), __float_as_uint(p0), 0x07060302u); \
        pk_[mt][1] = __builtin_amdgcn_perm(__float_as_uint(p3), __float_as_uint(p2), 0x07060302u); \
    } \
    _Pragma("unroll") \
    for (int ks=0;ks<2;ks++){ \
        union { unsigned int u[4]; bf16x8 v; } pB_; \
        pB_.u[0] = pk_[2*ks][0];   pB_.u[1] = pk_[2*ks][1]; \
        pB_.u[2] = pk_[2*ks+1][0]; pB_.u[3] = pk_[2*ks+1][1]; \
        _Pragma("unroll") \
        for (int nt=0;nt<4;nt++){ \
            const int dv_ = nt*16 + c; \
            const unsigned short* vbase_ = VTB + dv_*64; \
            int flo_ = quad*4 + (((dv_>>1) + ks*2    )&3); \
            int fhi_ = quad*4 + (((dv_>>1) + ks*2 + 1)&3); \
            uint2 lo_ = *(const uint2*)(vbase_ + flo_*4); \
            uint2 hi_ = *(const uint2*)(vbase_ + fhi_*4); \
            union { unsigned int u[4]; bf16x8 v; } vv_; \
            vv_.u[0]=lo_.x; vv_.u[1]=lo_.y; vv_.u[2]=hi_.x; vv_.u[3]=hi_.y; \
            o[nt] = MFMA(vv_.v, pB_.v, o[nt]); \
        } \
    } }while(0)

    STAGE2(kb, KT0); STAGE2(vb, VT0);
    __syncthreads();

    for (int kt2=0; kt2<SEQ/64; kt2+=2){
        STAGE2(kb + (kt2+1)*4096, KT1);   // kt2+1 <= 31 always
        STAGE2(vb + (kt2+1)*4096, VT1);
        ATTN_TILE(KT0, VT0);
        __syncthreads();
        if (kt2+2 < SEQ/64){
            STAGE2(kb + (kt2+2)*4096, KT0);
            STAGE2(vb + (kt2+2)*4096, VT0);
        }
        ATTN_TILE(KT1, VT1);
        __syncthreads();
    }
#undef STAGE2
#undef ATTN_TILE

    // denominator: lane-local partial for qrow c; reduce across quads.
    float l_loc = (l4[0]+l4[1]) + (l4[2]+l4[3]);
    l_loc += __shfl_xor(l_loc, 16, 64);
    l_loc += __shfl_xor(l_loc, 32, 64);
    float inv = 1.0f / l_loc;

    const int b = bh >> 4, h = bh & 15;
    long base = ((long)(b*SEQ + qbase + c)*NH + h)*HD;
    #pragma unroll
    for (int nt=0;nt<4;nt++){
        us4 pkd;
        #pragma unroll
        for (int r=0;r<4;r++) pkd[r] = f2bf(o[nt][r]*inv);
        *(us4*)(abuf + base + nt*16 + quad*4) = pkd;
    }
}

// ---------------------------------------------------------------------------
// Kernel 3: out = attn @ Wproj^T + bproj. 128x64 tile, BK=32, static-name
// double-buffered prefetch + __syncthreads (R7 form — counted-vmcnt
// REGRESSED proj ~14us in R8). 512 blocks = 2/CU. Inline dtype detection
// for the output-format flag.
// ---------------------------------------------------------------------------
__global__ __launch_bounds__(256) void proj_kernel(
    const unsigned short* __restrict__ abuf,
    const unsigned short* __restrict__ Wp,
    const unsigned short* __restrict__ bp,
    void* __restrict__ outv,
    const unsigned int* __restrict__ xraw)
{
    __shared__ __align__(16) unsigned short tA0[128*32];
    __shared__ __align__(16) unsigned short tA1[128*32];
    __shared__ __align__(16) unsigned short tB0[64*32];
    __shared__ __align__(16) unsigned short tB1[64*32];
    __shared__ int cnts[4];
    const int tid  = threadIdx.x;
    const int flag = detect_flag(xraw, tid, cnts);
    const int w    = tid >> 6, lane = tid & 63, quad = lane >> 4, c = lane & 15;
    const int m0 = blockIdx.y*128, n0 = blockIdx.x*64;
    const int am = (w>>1)*64, bn = (w&1)*32;
    const int kq = quad ^ ((c>>1)&3);

    f32x4 acc[4][2];
    for (int mi=0;mi<4;mi++) for (int ni=0;ni<2;ni++) acc[mi][ni] = {0.f,0.f,0.f,0.f};

    const int i0 = tid, i1 = tid + 256;
    const int r0 = i0>>2, cc0 = (i0&3) ^ ((r0>>1)&3);
    const int r1 = i1>>2, cc1 = (i1&3) ^ ((r1>>1)&3);
    const long gaA0 = (long)(m0 + r0)*D_MODEL + cc0*8;
    const long gaA1 = (long)(m0 + r1)*D_MODEL + cc1*8;
    const long gbB0 = (long)(n0 + r0)*D_MODEL + cc0*8;   // r0 < 64 for B

#define PROJ_STAGE(BUFA, BUFB, T) do{ const int kk_ = (T)*32; \
    g2l16(abuf + gaA0 + kk_, BUFA + i0*8); \
    g2l16(abuf + gaA1 + kk_, BUFA + i1*8); \
    g2l16(Wp   + gbB0 + kk_, BUFB + i0*8); }while(0)

#define PROJ_COMP(BUFA, BUFB) do{ \
    bf16x8 a_[4], b_[2]; \
    _Pragma("unroll") \
    for (int mi=0;mi<4;mi++) \
        a_[mi] = *(const bf16x8*)(BUFA + ((am + mi*16 + c)*4 + kq)*8); \
    _Pragma("unroll") \
    for (int ni=0;ni<2;ni++) \
        b_[ni] = *(const bf16x8*)(BUFB + ((bn + ni*16 + c)*4 + kq)*8); \
    _Pragma("unroll") \
    for (int mi=0;mi<4;mi++) \
        _Pragma("unroll") \
        for (int ni=0;ni<2;ni++) \
            acc[mi][ni] = MFMA(a_[mi], b_[ni], acc[mi][ni]); }while(0)

    PROJ_STAGE(tA0, tB0, 0);
    __syncthreads();

    for (int t=0; t<32; t+=2){
        PROJ_STAGE(tA1, tB1, t+1);       // t+1 <= 31 always
        PROJ_COMP(tA0, tB0);
        __syncthreads();
        if (t+2 < 32) PROJ_STAGE(tA0, tB0, t+2);
        PROJ_COMP(tA1, tB1);
        __syncthreads();
    }
#undef PROJ_STAGE
#undef PROJ_COMP

    float bias[2];
    for (int ni=0;ni<2;ni++) bias[ni] = b2f(bp[n0 + bn + ni*16 + c]);

    for (int mi=0;mi<4;mi++)
        for (int r=0;r<4;r++){
            long m = m0 + am + mi*16 + quad*4 + r;
            for (int ni=0;ni<2;ni++){
                float val = acc[mi][ni][r] + bias[ni];
                long idx = m*D_MODEL + n0 + bn + ni*16 + c;
                if (flag) ((float*)outv)[idx] = val;
                else      ((unsigned short*)outv)[idx] = f2bf(val);
            }
        }
}

extern "C" void kernel_launch(void* const* d_in, const int* in_sizes, int n_in,
                              void* d_out, int out_size, void* d_ws, size_t ws_size,
                              hipStream_t stream)
{
    unsigned short* ws = (unsigned short*)d_ws;

    hipLaunchKernelGGL(convert_kernel, dim3(2048), dim3(256), 0, stream,
                       d_in[0], d_in[1], d_in[2], d_in[3], d_in[4], d_in[5], d_in[6],
                       ws);
    hipLaunchKernelGGL(qkv_kernel,  dim3(24,32), dim3(256), 0, stream,
                       ws+OFF_X, ws+OFF_WQ, ws+OFF_BQ, ws+OFF_QN, ws+OFF_KN,
                       ws+OFF_Q, ws+OFF_K, ws+OFF_V);
    hipLaunchKernelGGL(attn_kernel, dim3(32,32), dim3(256), 0, stream,
                       ws+OFF_Q, ws+OFF_K, ws+OFF_V, ws+OFF_A);
    hipLaunchKernelGGL(proj_kernel, dim3(16,32), dim3(256), 0, stream,
                       ws+OFF_A, ws+OFF_WP, ws+OFF_BP, d_out,
                       (const unsigned int*)d_in[0]);
}